// Round 6
// baseline (550.733 us; speedup 1.0000x reference)
//
#include <hip/hip_runtime.h>
#include <hip/hip_bf16.h>
#include <cstddef>

// ============================================================================
// VLSTM via bf16 MFMA, R6: R4's proven 2-barrier skeleton, scaled to
// 128-node blocks with grid=256 (exactly 1 persistent block per CU).
//  - Per-CU barrier count halved (40 vs 80), no sequential 2nd block.
//  - Register-resident gate weights (96 VGPR/wave), W_out fragments in LDS.
//  - Gate GEMM in two 4-rt halves sharing one 64-reg accumulator; half-B's
//    independent ds_reads/MFMAs overlap half-A's activation VALU.
//  - Out-proj on ALL 8 waves (rt = wave), masked via the lane's own mbits.
//  - Packed bf16 converts (v_cvt_pk_bf16_f32) via __float22bfloat162_rn.
//  - LDS-staged coalesced out-stores (R4), single A buffer, masked h-writes.
// ============================================================================

typedef __attribute__((ext_vector_type(8))) short  s16x8;   // 8 x bf16
typedef __attribute__((ext_vector_type(4))) float  f32x4;

namespace {
constexpr int T_STEPS = 20;
constexpr int NN      = 32768;
constexpr int D_EMB   = 64;
constexpr int D_H     = 128;
constexpr int D_OUT   = 5;
constexpr int G4      = 512;
constexpr int MT      = 128;           // nodes per block
constexpr int BLOCK   = 512;           // 8 waves
constexpr int GRID    = NN / MT;       // 256 = one block per CU
constexpr int WP_ELEMS   = 8 * 4 * 6 * 64 * 8;
constexpr int WOUT_ELEMS = 4 * 64 * 8;
constexpr int AELEMS  = 8 * 6 * 64 * 8;          // 24576 shorts = 48 KB
constexpr size_t OFF_H = (size_t)T_STEPS * NN * D_OUT;
constexpr size_t OFF_C = OFF_H + (size_t)NN * D_H;
}

__device__ __forceinline__ unsigned short f2bf(float x) {
    unsigned u = __float_as_uint(x);
    u = (u + 0x7FFFu + ((u >> 16) & 1u)) >> 16;     // RNE
    return (unsigned short)u;
}
__device__ __forceinline__ float bf2f(unsigned short h) {
    return __uint_as_float(((unsigned)h) << 16);
}
__device__ __forceinline__ unsigned pk2bf(float lo, float hi) {
    __hip_bfloat162 p = __float22bfloat162_rn(make_float2(lo, hi));
    return *(unsigned*)&p;                           // v_cvt_pk_bf16_f32
}
__device__ __forceinline__ float sigf(float x) {
    return __builtin_amdgcn_rcpf(1.0f + __expf(-x));
}
__device__ __forceinline__ float tanhf_fast(float x) {
    return fmaf(-2.0f, __builtin_amdgcn_rcpf(1.0f + __expf(2.0f * x)), 1.0f);
}

// ----------------------------------------------------------------------------
// Pre-pack (identical layout to R4 — wave w owns units w*16..w*16+15):
//  Wp[w][g][kb][L][j] = Wcat[k=kb*32+(L>>4)*8+j][col=g*128+w*16+(L&15)]
//  WoutF[kb2][L][j]   = (L&15)<5 ? W_out[k=kb2*32+(L>>4)*8+j][L&15] : 0
// ----------------------------------------------------------------------------
__global__ void prepack_kernel(const float* __restrict__ W_ih,
                               const float* __restrict__ b_ih,
                               const float* __restrict__ W_hh,
                               const float* __restrict__ b_hh,
                               const float* __restrict__ W_out,
                               unsigned short* __restrict__ Wp,
                               unsigned short* __restrict__ WoutF,
                               float* __restrict__ b_sum) {
    int idx = blockIdx.x * blockDim.x + threadIdx.x;
    if (idx < WP_ELEMS) {
        int j    = idx & 7;
        int L    = (idx >> 3) & 63;
        int rest = idx >> 9;
        int kb   = rest % 6;
        int gw   = rest / 6;
        int g    = gw & 3, w = gw >> 2;
        int k    = kb * 32 + (L >> 4) * 8 + j;
        int col  = g * D_H + w * 16 + (L & 15);
        float v  = (k < D_EMB) ? W_ih[k * G4 + col] : W_hh[(k - D_EMB) * G4 + col];
        Wp[idx] = f2bf(v);
    } else if (idx < WP_ELEMS + WOUT_ELEMS) {
        int i2 = idx - WP_ELEMS;
        int j = i2 & 7, L = (i2 >> 3) & 63, kb2 = i2 >> 9;
        int k = kb2 * 32 + (L >> 4) * 8 + j;
        int n = L & 15;
        WoutF[i2] = (n < D_OUT) ? f2bf(W_out[k * D_OUT + n]) : (unsigned short)0;
    }
    if (idx < G4) b_sum[idx] = b_ih[idx] + b_hh[idx];
}

// ----------------------------------------------------------------------------
__global__ __launch_bounds__(BLOCK, 2) void vlstm_kernel(
    const float* __restrict__ nodes,   // [T][N][2]
    const int*   __restrict__ mask,    // [T][N]
    const float* __restrict__ h0,      // [N][128]
    const float* __restrict__ c0,      // [N][128]
    const float* __restrict__ W_embed, // [2][64]
    const float* __restrict__ b_embed, // [64]
    const float* __restrict__ b_out,   // [5]
    const unsigned short* __restrict__ Wp,
    const unsigned short* __restrict__ WoutF,
    const float* __restrict__ b_sum,
    float* __restrict__ out)
{
    __shared__ __align__(16) unsigned short A[AELEMS];        // 48 KB frag-order
    __shared__ __align__(16) unsigned short WoF_s[WOUT_ELEMS];// 4 KB
    __shared__ __align__(16) float st_out[MT * D_OUT];        // 2.5 KB
    __shared__ float We_s[2 * D_EMB];
    __shared__ float be_s[D_EMB];
    __shared__ int   msk_s[2][MT];

    const int tid  = threadIdx.x;
    const int wave = tid >> 6;
    const int L    = tid & 63;
    const int quad = L >> 4;
    const int l15  = L & 15;
    const int n_base = blockIdx.x * MT;

    // ---- gate weights -> registers, once ----
    const unsigned short* wbase = Wp + (size_t)wave * (4 * 6 * 64 * 8);
    s16x8 Bf[4][6];
    #pragma unroll
    for (int g = 0; g < 4; g++)
        #pragma unroll
        for (int kb = 0; kb < 6; kb++)
            Bf[g][kb] = *(const s16x8*)(wbase + ((g * 6 + kb) * 64 + L) * 8);

    float bias[4];
    #pragma unroll
    for (int g = 0; g < 4; g++) bias[g] = b_sum[g * D_H + wave * 16 + l15];
    const float bo = (l15 < D_OUT) ? b_out[l15] : 0.0f;

    // ---- one-time LDS staging ----
    for (int i = tid; i < WOUT_ELEMS / 8; i += BLOCK)
        *(s16x8*)(WoF_s + i * 8) = *(const s16x8*)(WoutF + i * 8);
    for (int i = tid; i < 3 * D_EMB; i += BLOCK) {
        if (i < 2 * D_EMB) We_s[i] = W_embed[i];
        else               be_s[i - 2 * D_EMB] = b_embed[i - 2 * D_EMB];
    }
    for (int i = tid; i < MT * D_H; i += BLOCK) {   // h0 -> A h-region
        int node = i >> 7, u = i & 127;
        int k = D_EMB + u;
        int idx = (((node >> 4) * 6 + (k >> 5)) * 64 + ((k >> 3) & 3) * 16 + (node & 15)) * 8 + (k & 7);
        A[idx] = f2bf(h0[(size_t)(n_base + node) * D_H + u]);
    }
    const int u_lane = wave * 16 + l15;
    float c[8][4];                                  // [rt][r]
    #pragma unroll
    for (int rt = 0; rt < 8; rt++)
        #pragma unroll
        for (int r = 0; r < 4; r++) {
            int m = rt * 16 + quad * 4 + r;
            c[rt][r] = c0[(size_t)(n_base + m) * D_H + u_lane];
        }

    const int node_e = tid >> 3;    // emb: this thread handles node_e, node_e+64
    const int eb     = tid & 7;

    // ---- emb(0) + mask(0) ----
    {
        #pragma unroll
        for (int h = 0; h < 2; h++) {
            int node = node_e + 64 * h;
            float2 x = *(const float2*)(nodes + ((size_t)0 * NN + n_base + node) * 2);
            union { s16x8 v; unsigned u[4]; } ev;
            #pragma unroll
            for (int jp = 0; jp < 4; jp++) {
                int e = eb * 8 + jp * 2;
                float v0 = fmaf(x.x, We_s[e],     fmaf(x.y, We_s[D_EMB + e],     be_s[e]));
                float v1 = fmaf(x.x, We_s[e + 1], fmaf(x.y, We_s[D_EMB + e + 1], be_s[e + 1]));
                ev.u[jp] = pk2bf(fmaxf(v0, 0.0f), fmaxf(v1, 0.0f));
            }
            int idx = (((node >> 4) * 6 + (eb >> 2)) * 64 + (eb & 3) * 16 + (node & 15)) * 8;
            *(s16x8*)(A + idx) = ev.v;
        }
        if (tid < MT) msk_s[0][tid] = mask[(size_t)0 * NN + n_base + tid];
    }
    __syncthreads();

    // h-write address components (lane's own units)
    const int kb_u = 2 + (u_lane >> 5);
    const int fl   = ((u_lane >> 3) & 3) * 16 + quad * 4;
    const int j_u  = u_lane & 7;

    for (int t = 0; t < T_STEPS; t++) {
        const int p = t & 1;
        const bool has_next = (t + 1 < T_STEPS);

        // ---- prefetch x(t+1) / mask(t+1) into registers ----
        float2 xv[2] = {{0.f, 0.f}, {0.f, 0.f}};
        int mpf = 0;
        if (has_next) {
            xv[0] = *(const float2*)(nodes + ((size_t)(t + 1) * NN + n_base + node_e) * 2);
            xv[1] = *(const float2*)(nodes + ((size_t)(t + 1) * NN + n_base + node_e + 64) * 2);
            if (tid < MT) mpf = mask[(size_t)(t + 1) * NN + n_base + tid];
        }

        // ---- gate GEMM + activations, two 4-rt halves sharing acc ----
        unsigned mbits = 0;
        unsigned hpk[8][2];     // packed bf16 h-new, [rt][r-pair]
        #pragma unroll
        for (int half = 0; half < 2; half++) {
            f32x4 acc[4][4];   // [rt-in-half][gate]
            #pragma unroll
            for (int q = 0; q < 4; q++)
                #pragma unroll
                for (int g = 0; g < 4; g++)
                    acc[q][g] = (f32x4){bias[g], bias[g], bias[g], bias[g]};
            #pragma unroll
            for (int kb = 0; kb < 6; kb++) {
                #pragma unroll
                for (int q = 0; q < 4; q++) {
                    int rt = half * 4 + q;
                    s16x8 af = *(const s16x8*)(A + ((rt * 6 + kb) * 64 + L) * 8);
                    #pragma unroll
                    for (int g = 0; g < 4; g++)
                        acc[q][g] = __builtin_amdgcn_mfma_f32_16x16x32_bf16(
                            af, Bf[g][kb], acc[q][g], 0, 0, 0);
                }
            }
            #pragma unroll
            for (int q = 0; q < 4; q++) {
                int rt = half * 4 + q;
                float hv[4];
                #pragma unroll
                for (int r = 0; r < 4; r++) {
                    int m = rt * 16 + quad * 4 + r;
                    int mval = msk_s[p][m];
                    float gi = sigf(acc[q][0][r]);
                    float gf = sigf(acc[q][1][r]);
                    float gg = tanhf_fast(acc[q][2][r]);
                    float go = sigf(acc[q][3][r]);
                    float cn = fmaf(gf, c[rt][r], gi * gg);
                    hv[r] = go * tanhf_fast(cn);
                    if (mval) { c[rt][r] = cn; mbits |= 1u << (rt * 4 + r); }
                }
                hpk[rt][0] = pk2bf(hv[0], hv[1]);
                hpk[rt][1] = pk2bf(hv[2], hv[3]);
            }
        }
        __syncthreads();   // B2(t): all GEMM reads of A done; st_out(t-1) ready

        // ---- coalesced store of out(t-1) from staging ----
        if (t > 0)
            for (int i = tid; i < MT * D_OUT; i += BLOCK)
                out[((size_t)(t - 1) * NN + n_base) * D_OUT + i] = st_out[i];

        // ---- h-write (masked) into A h-region ----
        #pragma unroll
        for (int rt = 0; rt < 8; rt++)
            #pragma unroll
            for (int r = 0; r < 4; r++)
                if ((mbits >> (rt * 4 + r)) & 1u)
                    A[((rt * 6 + kb_u) * 64 + fl + r) * 8 + j_u] =
                        (unsigned short)(hpk[rt][r >> 1] >> ((r & 1) * 16));

        // ---- emb(t+1) + mask(t+1) ----
        if (has_next) {
            #pragma unroll
            for (int h = 0; h < 2; h++) {
                int node = node_e + 64 * h;
                union { s16x8 v; unsigned u[4]; } ev;
                #pragma unroll
                for (int jp = 0; jp < 4; jp++) {
                    int e = eb * 8 + jp * 2;
                    float v0 = fmaf(xv[h].x, We_s[e],     fmaf(xv[h].y, We_s[D_EMB + e],     be_s[e]));
                    float v1 = fmaf(xv[h].x, We_s[e + 1], fmaf(xv[h].y, We_s[D_EMB + e + 1], be_s[e + 1]));
                    ev.u[jp] = pk2bf(fmaxf(v0, 0.0f), fmaxf(v1, 0.0f));
                }
                int idx = (((node >> 4) * 6 + (eb >> 2)) * 64 + (eb & 3) * 16 + (node & 15)) * 8;
                *(s16x8*)(A + idx) = ev.v;
            }
            if (tid < MT) msk_s[1 - p][tid] = mpf;
        }
        __syncthreads();   // B3(t): new h + next emb/mask visible

        // ---- out-proj(t): ALL 8 waves (rt = wave), mask from own mbits ----
        // Same barrier-free region as GEMM(t+1): A h-rows stable until the
        // h-write after B2(t+1); st_out read happens right after B2(t+1).
        {
            const int rt = wave;
            f32x4 ao = (f32x4){0.0f, 0.0f, 0.0f, 0.0f};
            #pragma unroll
            for (int kb2 = 0; kb2 < 4; kb2++) {
                s16x8 af = *(const s16x8*)(A + ((rt * 6 + 2 + kb2) * 64 + L) * 8);
                s16x8 wf = *(const s16x8*)(WoF_s + (kb2 * 64 + L) * 8);
                ao = __builtin_amdgcn_mfma_f32_16x16x32_bf16(af, wf, ao, 0, 0, 0);
            }
            if (l15 < D_OUT) {
                #pragma unroll
                for (int r = 0; r < 4; r++) {
                    int node = rt * 16 + quad * 4 + r;
                    st_out[node * D_OUT + l15] =
                        ((mbits >> (rt * 4 + r)) & 1u) ? (ao[r] + bo) : 0.0f;
                }
            }
        }
    }

    __syncthreads();   // st_out(T-1) visible
    for (int i = tid; i < MT * D_OUT; i += BLOCK)
        out[((size_t)(T_STEPS - 1) * NN + n_base) * D_OUT + i] = st_out[i];

    // ---- epilogue: h_fin from A (bf16), c_fin exact fp32 from regs ----
    for (int i = tid; i < MT * D_H; i += BLOCK) {
        int node = i >> 7, u = i & 127;
        int k = D_EMB + u;
        int idx = (((node >> 4) * 6 + (k >> 5)) * 64 + ((k >> 3) & 3) * 16 + (node & 15)) * 8 + (k & 7);
        out[OFF_H + (size_t)(n_base + node) * D_H + u] = bf2f(A[idx]);
    }
    #pragma unroll
    for (int rt = 0; rt < 8; rt++)
        #pragma unroll
        for (int r = 0; r < 4; r++) {
            int m = rt * 16 + quad * 4 + r;
            out[OFF_C + (size_t)(n_base + m) * D_H + u_lane] = c[rt][r];
        }
}

extern "C" void kernel_launch(void* const* d_in, const int* in_sizes, int n_in,
                              void* d_out, int out_size, void* d_ws, size_t ws_size,
                              hipStream_t stream) {
    const float* nodes   = (const float*)d_in[0];
    const int*   mask    = (const int*)  d_in[1];
    const float* h0      = (const float*)d_in[2];
    const float* c0      = (const float*)d_in[3];
    const float* W_embed = (const float*)d_in[4];
    const float* b_embed = (const float*)d_in[5];
    const float* W_ih    = (const float*)d_in[6];
    const float* b_ih    = (const float*)d_in[7];
    const float* W_hh    = (const float*)d_in[8];
    const float* b_hh    = (const float*)d_in[9];
    const float* W_out   = (const float*)d_in[10];
    const float* b_out   = (const float*)d_in[11];
    float* out = (float*)d_out;

    unsigned short* Wp    = (unsigned short*)d_ws;
    unsigned short* WoutF = Wp + WP_ELEMS;
    float*          b_sum = (float*)(WoutF + WOUT_ELEMS);

    prepack_kernel<<<(WP_ELEMS + WOUT_ELEMS + 255) / 256, 256, 0, stream>>>(
        W_ih, b_ih, W_hh, b_hh, W_out, Wp, WoutF, b_sum);

    vlstm_kernel<<<GRID, BLOCK, 0, stream>>>(
        nodes, mask, h0, c0, W_embed, b_embed, b_out, Wp, WoutF, b_sum, out);
}

// Round 7
// 509.882 us; speedup vs baseline: 1.0801x; 1.0801x over previous
//
#include <hip/hip_runtime.h>
#include <hip/hip_bf16.h>
#include <cstddef>

// ============================================================================
// VLSTM via bf16 MFMA, R7: 16-wave blocks with gate-split wave pairs.
//  - MT=64 nodes/block, BLOCK=1024 (16 waves), GRID=512, 2 rounds/CU.
//  - Wave pair (2ug, 2ug+1) owns unit-group ug (units 16ug..16ug+15):
//      even wave: gates {i,f};  odd wave: gates {g,o}.
//    Per-wave weights drop 96 -> 48 VGPR; acc 64 -> 32 AGPR; peak ~115 regs
//    -> __launch_bounds__(1024,4) = 4 waves/SIMD (vs R4's 2).
//  - Activation split: odd lane (ug,L) computes tanh(g), sig(o) for exactly
//    the (node,unit) elements even lane (ug,L) owns; packed bf16x2 handoff
//    through LDS X (stride 17 -> conflict-free), synced by the existing B2.
//  - Out-proj on odd waves 1,3,5,7 (rt = ug), WoF in their spare registers.
//  - Everything else identical to R4 (proven 258 us, FETCH at ideal):
//    2 barriers/step, masked h-writes, LDS-staged coalesced out stores.
// ============================================================================

typedef __attribute__((ext_vector_type(8))) short  s16x8;   // 8 x bf16
typedef __attribute__((ext_vector_type(4))) float  f32x4;

namespace {
constexpr int T_STEPS = 20;
constexpr int NN      = 32768;
constexpr int D_EMB   = 64;
constexpr int D_H     = 128;
constexpr int D_OUT   = 5;
constexpr int G4      = 512;
constexpr int MT      = 64;
constexpr int BLOCK   = 1024;          // 16 waves
constexpr int GRID    = NN / MT;       // 512
constexpr int WP_ELEMS   = 16 * 2 * 6 * 64 * 8;  // 98304 (same bytes as R4)
constexpr int WOUT_ELEMS = 4 * 64 * 8;
constexpr int AELEMS  = 24 * 64 * 8;             // 24 KB A buffer
constexpr size_t OFF_H = (size_t)T_STEPS * NN * D_OUT;
constexpr size_t OFF_C = OFF_H + (size_t)NN * D_H;
}

__device__ __forceinline__ unsigned short f2bf(float x) {
    unsigned u = __float_as_uint(x);
    u = (u + 0x7FFFu + ((u >> 16) & 1u)) >> 16;     // RNE
    return (unsigned short)u;
}
__device__ __forceinline__ float bf2f(unsigned short h) {
    return __uint_as_float(((unsigned)h) << 16);
}
__device__ __forceinline__ unsigned pk2bf(float lo, float hi) {
    __hip_bfloat162 p = __float22bfloat162_rn(make_float2(lo, hi));
    return *(unsigned*)&p;                           // v_cvt_pk_bf16_f32
}
__device__ __forceinline__ float sigf(float x) {
    return __builtin_amdgcn_rcpf(1.0f + __expf(-x));
}
__device__ __forceinline__ float tanhf_fast(float x) {
    return fmaf(-2.0f, __builtin_amdgcn_rcpf(1.0f + __expf(2.0f * x)), 1.0f);
}

// ----------------------------------------------------------------------------
// Pre-pack:
//  Wp[w][gg][kb][L][j] = Wcat[k=kb*32+(L>>4)*8+j][col=gate*128+ug*16+(L&15)]
//    where ug = w>>1, gate = (w&1)*2+gg   (even wave: i,f; odd wave: g,o)
//  WoutF[kb2][L][j]    = (L&15)<5 ? W_out[k=kb2*32+(L>>4)*8+j][L&15] : 0
// ----------------------------------------------------------------------------
__global__ void prepack_kernel(const float* __restrict__ W_ih,
                               const float* __restrict__ b_ih,
                               const float* __restrict__ W_hh,
                               const float* __restrict__ b_hh,
                               const float* __restrict__ W_out,
                               unsigned short* __restrict__ Wp,
                               unsigned short* __restrict__ WoutF,
                               float* __restrict__ b_sum) {
    int idx = blockIdx.x * blockDim.x + threadIdx.x;
    if (idx < WP_ELEMS) {
        int j    = idx & 7;
        int L    = (idx >> 3) & 63;
        int rest = idx >> 9;
        int kb   = rest % 6;
        int wg   = rest / 6;            // w*2 + gg
        int gg   = wg & 1, w = wg >> 1;
        int ug   = w >> 1;
        int gate = (w & 1) * 2 + gg;
        int k    = kb * 32 + (L >> 4) * 8 + j;
        int col  = gate * D_H + ug * 16 + (L & 15);
        float v  = (k < D_EMB) ? W_ih[k * G4 + col] : W_hh[(k - D_EMB) * G4 + col];
        Wp[idx] = f2bf(v);
    } else if (idx < WP_ELEMS + WOUT_ELEMS) {
        int i2 = idx - WP_ELEMS;
        int j = i2 & 7, L = (i2 >> 3) & 63, kb2 = i2 >> 9;
        int k = kb2 * 32 + (L >> 4) * 8 + j;
        int n = L & 15;
        WoutF[i2] = (n < D_OUT) ? f2bf(W_out[k * D_OUT + n]) : (unsigned short)0;
    }
    if (idx < G4) b_sum[idx] = b_ih[idx] + b_hh[idx];
}

// ----------------------------------------------------------------------------
__global__ __launch_bounds__(BLOCK, 4) void vlstm_kernel(
    const float* __restrict__ nodes,   // [T][N][2]
    const int*   __restrict__ mask,    // [T][N]
    const float* __restrict__ h0,      // [N][128]
    const float* __restrict__ c0,      // [N][128]
    const float* __restrict__ W_embed, // [2][64]
    const float* __restrict__ b_embed, // [64]
    const float* __restrict__ b_out,   // [5]
    const unsigned short* __restrict__ Wp,
    const unsigned short* __restrict__ WoutF,
    const float* __restrict__ b_sum,
    float* __restrict__ out)
{
    __shared__ __align__(16) unsigned short A[AELEMS];     // 24576 B
    __shared__ __align__(16) unsigned Xex[8 * 64 * 17];    // 34816 B exchange
    __shared__ __align__(16) float st_out[MT * D_OUT];     // 1280 B
    __shared__ float We_s[2 * D_EMB];                      // 512 B
    __shared__ float be_s[D_EMB];                          // 256 B
    __shared__ int   msk_s[2][MT];                         // 512 B

    const int tid  = threadIdx.x;
    const int wave = tid >> 6;        // 0..15
    const int aodd = wave & 1;        // 0: gates i,f ; 1: gates g,o
    const int ug   = wave >> 1;       // unit group 0..7
    const int L    = tid & 63;
    const int quad = L >> 4;
    const int l15  = L & 15;
    const int n_base = blockIdx.x * MT;
    const int u_lane = ug * 16 + l15;

    // ---- gate weights -> registers, once (2 gates x 6 kb = 48 VGPR) ----
    const unsigned short* wbase = Wp + (size_t)wave * (2 * 6 * 64 * 8);
    s16x8 Bf[2][6];
    #pragma unroll
    for (int gg = 0; gg < 2; gg++)
        #pragma unroll
        for (int kb = 0; kb < 6; kb++)
            Bf[gg][kb] = *(const s16x8*)(wbase + ((gg * 6 + kb) * 64 + L) * 8);

    float bias[2];
    #pragma unroll
    for (int gg = 0; gg < 2; gg++)
        bias[gg] = b_sum[(aodd * 2 + gg) * D_H + u_lane];

    // ---- out-proj fragments: only odd waves 1,3,5,7 ----
    s16x8 WoF[4];
    const int do_oproj = (aodd == 1 && ug < 4);
    if (do_oproj) {
        #pragma unroll
        for (int kb2 = 0; kb2 < 4; kb2++)
            WoF[kb2] = *(const s16x8*)(WoutF + ((kb2 * 64) + L) * 8);
    }
    const float bo = (l15 < D_OUT) ? b_out[l15] : 0.0f;

    // ---- one-time LDS staging ----
    for (int i = tid; i < 3 * D_EMB; i += BLOCK) {
        if (i < 2 * D_EMB) We_s[i] = W_embed[i];
        else               be_s[i - 2 * D_EMB] = b_embed[i - 2 * D_EMB];
    }
    for (int i = tid; i < MT * D_H; i += BLOCK) {   // h0 -> A h-region
        int node = i >> 7, u = i & 127;
        int k = D_EMB + u;
        int idx = (((node >> 4) * 6 + (k >> 5)) * 64 + ((k >> 3) & 3) * 16 + (node & 15)) * 8 + (k & 7);
        A[idx] = f2bf(h0[(size_t)(n_base + node) * D_H + u]);
    }
    // ---- c state: even waves own it ----
    float c[4][4];
    if (aodd == 0) {
        #pragma unroll
        for (int rt = 0; rt < 4; rt++)
            #pragma unroll
            for (int r = 0; r < 4; r++) {
                int m = rt * 16 + quad * 4 + r;
                c[rt][r] = c0[(size_t)(n_base + m) * D_H + u_lane];
            }
    }

    const int node_e = tid >> 4;      // 64 nodes, 16 threads each
    const int eb     = tid & 15;      // 4 e-values per thread

    // ---- emb(0) + mask(0) ----
    {
        float2 x = *(const float2*)(nodes + ((size_t)0 * NN + n_base + node_e) * 2);
        int e0 = eb * 4;
        float v0 = fmaf(x.x, We_s[e0],     fmaf(x.y, We_s[D_EMB + e0],     be_s[e0]));
        float v1 = fmaf(x.x, We_s[e0 + 1], fmaf(x.y, We_s[D_EMB + e0 + 1], be_s[e0 + 1]));
        float v2 = fmaf(x.x, We_s[e0 + 2], fmaf(x.y, We_s[D_EMB + e0 + 2], be_s[e0 + 2]));
        float v3 = fmaf(x.x, We_s[e0 + 3], fmaf(x.y, We_s[D_EMB + e0 + 3], be_s[e0 + 3]));
        uint2 pk;
        pk.x = pk2bf(fmaxf(v0, 0.0f), fmaxf(v1, 0.0f));
        pk.y = pk2bf(fmaxf(v2, 0.0f), fmaxf(v3, 0.0f));
        int idx = (((node_e >> 4) * 6 + (e0 >> 5)) * 64 + ((e0 >> 3) & 3) * 16 + (node_e & 15)) * 8 + (e0 & 7);
        *(uint2*)(A + idx) = pk;
        if (tid < MT) msk_s[0][tid] = mask[(size_t)0 * NN + n_base + tid];
    }
    __syncthreads();

    // h-write address components (even waves write their own units)
    const int kb_u = 2 + (u_lane >> 5);
    const int fl   = ((u_lane >> 3) & 3) * 16 + quad * 4;
    const int j_u  = u_lane & 7;
    const int xbase = (ug * 64 + L) * 17;

    for (int t = 0; t < T_STEPS; t++) {
        const int p = t & 1;
        const bool has_next = (t + 1 < T_STEPS);

        // ---- prefetch x(t+1) / mask(t+1) ----
        float2 xv = {0.0f, 0.0f};
        int mpf = 0;
        if (has_next) {
            xv = *(const float2*)(nodes + ((size_t)(t + 1) * NN + n_base + node_e) * 2);
            if (tid < MT) mpf = mask[(size_t)(t + 1) * NN + n_base + tid];
        }

        // ---- gate GEMM: 24 ds_read_b128 + 48 MFMA per wave ----
        f32x4 acc[4][2];
        #pragma unroll
        for (int rt = 0; rt < 4; rt++)
            #pragma unroll
            for (int gg = 0; gg < 2; gg++)
                acc[rt][gg] = (f32x4){bias[gg], bias[gg], bias[gg], bias[gg]};
        #pragma unroll
        for (int kb = 0; kb < 6; kb++) {
            #pragma unroll
            for (int rt = 0; rt < 4; rt++) {
                s16x8 af = *(const s16x8*)(A + ((rt * 6 + kb) * 64 + L) * 8);
                acc[rt][0] = __builtin_amdgcn_mfma_f32_16x16x32_bf16(af, Bf[0][kb], acc[rt][0], 0, 0, 0);
                acc[rt][1] = __builtin_amdgcn_mfma_f32_16x16x32_bf16(af, Bf[1][kb], acc[rt][1], 0, 0, 0);
            }
        }

        // ---- odd: tanh(g), sig(o) -> packed bf16x2 -> X exchange ----
        if (aodd == 1) {
            #pragma unroll
            for (int rt = 0; rt < 4; rt++) {
                uint4 xw;
                xw.x = pk2bf(tanhf_fast(acc[rt][0][0]), sigf(acc[rt][1][0]));
                xw.y = pk2bf(tanhf_fast(acc[rt][0][1]), sigf(acc[rt][1][1]));
                xw.z = pk2bf(tanhf_fast(acc[rt][0][2]), sigf(acc[rt][1][2]));
                xw.w = pk2bf(tanhf_fast(acc[rt][0][3]), sigf(acc[rt][1][3]));
                *(uint4*)(Xex + xbase + rt * 4) = xw;
            }
        }
        __syncthreads();   // B2(t): GEMM A-reads done, X visible, st_out(t-1) ready

        // ---- coalesced store of out(t-1) from staging ----
        if (t > 0 && tid < MT * D_OUT)
            out[((size_t)(t - 1) * NN + n_base) * D_OUT + tid] = st_out[tid];

        // ---- even: sig(i), sig(f), combine with X, update c, write h ----
        if (aodd == 0) {
            #pragma unroll
            for (int rt = 0; rt < 4; rt++) {
                uint4 xr = *(const uint4*)(Xex + xbase + rt * 4);
                unsigned xa[4] = {xr.x, xr.y, xr.z, xr.w};
                #pragma unroll
                for (int r = 0; r < 4; r++) {
                    int m = rt * 16 + quad * 4 + r;
                    int mval = msk_s[p][m];
                    float si = sigf(acc[rt][0][r]);
                    float sf = sigf(acc[rt][1][r]);
                    float tg = bf2f((unsigned short)(xa[r] & 0xFFFFu));
                    float so = bf2f((unsigned short)(xa[r] >> 16));
                    float cn = fmaf(sf, c[rt][r], si * tg);
                    float hv = so * tanhf_fast(cn);
                    if (mval) {
                        c[rt][r] = cn;
                        A[((rt * 6 + kb_u) * 64 + fl + r) * 8 + j_u] = f2bf(hv);
                    }
                }
            }
        }

        // ---- emb(t+1) + mask(t+1) (all threads) ----
        if (has_next) {
            int e0 = eb * 4;
            float v0 = fmaf(xv.x, We_s[e0],     fmaf(xv.y, We_s[D_EMB + e0],     be_s[e0]));
            float v1 = fmaf(xv.x, We_s[e0 + 1], fmaf(xv.y, We_s[D_EMB + e0 + 1], be_s[e0 + 1]));
            float v2 = fmaf(xv.x, We_s[e0 + 2], fmaf(xv.y, We_s[D_EMB + e0 + 2], be_s[e0 + 2]));
            float v3 = fmaf(xv.x, We_s[e0 + 3], fmaf(xv.y, We_s[D_EMB + e0 + 3], be_s[e0 + 3]));
            uint2 pk;
            pk.x = pk2bf(fmaxf(v0, 0.0f), fmaxf(v1, 0.0f));
            pk.y = pk2bf(fmaxf(v2, 0.0f), fmaxf(v3, 0.0f));
            int idx = (((node_e >> 4) * 6 + (e0 >> 5)) * 64 + ((e0 >> 3) & 3) * 16 + (node_e & 15)) * 8 + (e0 & 7);
            *(uint2*)(A + idx) = pk;
            if (tid < MT) msk_s[1 - p][tid] = mpf;
        }
        __syncthreads();   // B3(t): new h + next emb/mask visible

        // ---- out-proj(t): odd waves 1,3,5,7 (rt = ug); evens roll into
        //      GEMM(t+1) immediately (A stable until h-write post-B2(t+1)) ----
        if (do_oproj) {
            const int rt = ug;
            f32x4 ao = (f32x4){0.0f, 0.0f, 0.0f, 0.0f};
            #pragma unroll
            for (int kb2 = 0; kb2 < 4; kb2++) {
                s16x8 af = *(const s16x8*)(A + ((rt * 6 + 2 + kb2) * 64 + L) * 8);
                ao = __builtin_amdgcn_mfma_f32_16x16x32_bf16(af, WoF[kb2], ao, 0, 0, 0);
            }
            if (l15 < D_OUT) {
                #pragma unroll
                for (int r = 0; r < 4; r++) {
                    int node = rt * 16 + quad * 4 + r;
                    st_out[node * D_OUT + l15] =
                        msk_s[p][node] ? (ao[r] + bo) : 0.0f;
                }
            }
        }
    }

    __syncthreads();   // st_out(T-1) visible
    if (tid < MT * D_OUT)
        out[((size_t)(T_STEPS - 1) * NN + n_base) * D_OUT + tid] = st_out[tid];

    // ---- epilogue: h_fin from A (bf16), c_fin exact fp32 (even waves) ----
    for (int i = tid; i < MT * D_H; i += BLOCK) {
        int node = i >> 7, u = i & 127;
        int k = D_EMB + u;
        int idx = (((node >> 4) * 6 + (k >> 5)) * 64 + ((k >> 3) & 3) * 16 + (node & 15)) * 8 + (k & 7);
        out[OFF_H + (size_t)(n_base + node) * D_H + u] = bf2f(A[idx]);
    }
    if (aodd == 0) {
        #pragma unroll
        for (int rt = 0; rt < 4; rt++)
            #pragma unroll
            for (int r = 0; r < 4; r++) {
                int m = rt * 16 + quad * 4 + r;
                out[OFF_C + (size_t)(n_base + m) * D_H + u_lane] = c[rt][r];
            }
    }
}

extern "C" void kernel_launch(void* const* d_in, const int* in_sizes, int n_in,
                              void* d_out, int out_size, void* d_ws, size_t ws_size,
                              hipStream_t stream) {
    const float* nodes   = (const float*)d_in[0];
    const int*   mask    = (const int*)  d_in[1];
    const float* h0      = (const float*)d_in[2];
    const float* c0      = (const float*)d_in[3];
    const float* W_embed = (const float*)d_in[4];
    const float* b_embed = (const float*)d_in[5];
    const float* W_ih    = (const float*)d_in[6];
    const float* b_ih    = (const float*)d_in[7];
    const float* W_hh    = (const float*)d_in[8];
    const float* b_hh    = (const float*)d_in[9];
    const float* W_out   = (const float*)d_in[10];
    const float* b_out   = (const float*)d_in[11];
    float* out = (float*)d_out;

    unsigned short* Wp    = (unsigned short*)d_ws;
    unsigned short* WoutF = Wp + WP_ELEMS;
    float*          b_sum = (float*)(WoutF + WOUT_ELEMS);

    prepack_kernel<<<(WP_ELEMS + WOUT_ELEMS + 255) / 256, 256, 0, stream>>>(
        W_ih, b_ih, W_hh, b_hh, W_out, Wp, WoutF, b_sum);

    vlstm_kernel<<<GRID, BLOCK, 0, stream>>>(
        nodes, mask, h0, c0, W_embed, b_embed, b_out, Wp, WoutF, b_sum, out);
}